// Round 2
// baseline (329.991 us; speedup 1.0000x reference)
//
#include <hip/hip_runtime.h>
#include <hip/hip_bf16.h>
#include <math.h>

#define MAXN    32
#define NPTS    16384
#define NPSI    65              // 2*MAXN+1 feature dim
#define RSTRIDE 104             // ushorts per psi row (208 B, 16B-aligned; K zero-padded to 96)
#define BT      128             // output tile edge per block
#define ROWB    (RSTRIDE * 2)   // 208 bytes/row
#define PANELB  (BT * ROWB)     // 26624 bytes per 128-row panel
#define NCHUNK  (2 * PANELB / 1024)  // 52 x 1KiB staging chunks

typedef __attribute__((ext_vector_type(8))) short  bf16x8;
typedef __attribute__((ext_vector_type(4))) float  f32x4;

__device__ inline ushort f2bf(float f) {
    union { float f; unsigned u; } v; v.f = f;
    unsigned u = v.u;
    u += 0x7FFFu + ((u >> 16) & 1u);   // round-to-nearest-even
    return (ushort)(u >> 16);
}

// ---------------- kernel 1: psi rows (bf16, padded) into workspace ----------
__global__ __launch_bounds__(256) void psi_kernel(
    const float* __restrict__ xs, const float* __restrict__ logits,
    ushort* __restrict__ psi)
{
    int pt = blockIdx.x * blockDim.x + threadIdx.x;
    if (pt >= NPTS) return;

    float x = xs[pt];
    x = fminf(1.0f, fmaxf(-1.0f, x));
    float s = sqrtf(fmaxf(0.0f, 1.0f - x * x));

    // softmax over 33 logits (redundant per thread; trivial)
    float m = -3.4e38f;
    #pragma unroll
    for (int n = 0; n <= MAXN; ++n) m = fmaxf(m, logits[n]);
    float sum = 0.0f;
    #pragma unroll
    for (int n = 0; n <= MAXN; ++n) sum += __expf(logits[n] - m);
    float inv = 1.0f / sum;

    ushort tmp[RSTRIDE];
    tmp[0] = f2bf(sqrtf(__expf(logits[0] - m) * inv));
    float Tm1 = 1.0f, T = x;        // T_0, T_1
    float Um1 = 1.0f, U = 2.0f * x; // U_0, U_1
    float tx = 2.0f * x;
    #pragma unroll
    for (int n = 1; n <= MAXN; ++n) {
        float swn = sqrtf(__expf(logits[n] - m) * inv);
        tmp[2 * n - 1] = f2bf(swn * T);
        tmp[2 * n]     = f2bf(swn * (s * Um1));
        float Tn = tx * T - Tm1; Tm1 = T; T = Tn;
        float Un = tx * U - Um1; Um1 = U; U = Un;
    }
    #pragma unroll
    for (int k = NPSI; k < RSTRIDE; ++k) tmp[k] = 0;

    unsigned long long* dst = (unsigned long long*)(psi + (size_t)pt * RSTRIDE);
    const unsigned long long* src = (const unsigned long long*)tmp;
    #pragma unroll
    for (int k = 0; k < RSTRIDE / 4; ++k) dst[k] = src[k];
}

// ---------------- kernel 2: gram = psi @ psi^T, 128x128 tile per block ------
__device__ inline void load_lds16(const void* g, void* l) {
    __builtin_amdgcn_global_load_lds(
        (const __attribute__((address_space(1))) unsigned*)g,
        (__attribute__((address_space(3))) unsigned*)l, 16, 0, 0);
}

__global__ __launch_bounds__(256) void gram_kernel(
    const ushort* __restrict__ psi, float* __restrict__ out)
{
    __shared__ ushort lds[2 * BT * RSTRIDE];   // A panel rows 0..127, B panel rows 128..255

    const int tid  = threadIdx.x;
    const int w    = tid >> 6;     // wave 0..3: owns rows w*32 .. w*32+31
    const int lane = tid & 63;
    const int bi   = blockIdx.y;
    const int bj   = blockIdx.x;

    // stage 2 x 26624 B = 52 chunks of 1 KiB (64 lanes x 16 B each)
    {
        const char* gA = (const char*)(psi + (size_t)bi * BT * RSTRIDE);
        const char* gB = (const char*)(psi + (size_t)bj * BT * RSTRIDE);
        char* lbase = (char*)lds;
        for (int q = w; q < NCHUNK; q += 4) {
            const char* src = (q < 26) ? (gA + q * 1024) : (gB + (q - 26) * 1024);
            load_lds16(src + lane * 16, lbase + q * 1024);
        }
    }
    __syncthreads();

    const int lr = lane & 15;          // operand row index within 16-tile
    const int lk = (lane >> 4) * 8;    // k offset within 32-k-step

    // A panel rows = output rows (second mfma operand after swap)
    const ushort* aBase = lds + (w * 32 + lr) * RSTRIDE;
    // B panel rows = output cols (first mfma operand after swap)
    const ushort* bBase = lds + (BT + lr) * RSTRIDE;

    f32x4 acc[2][8];
    #pragma unroll
    for (int rt = 0; rt < 2; ++rt)
        #pragma unroll
        for (int ct = 0; ct < 8; ++ct) acc[rt][ct] = (f32x4){0.f, 0.f, 0.f, 0.f};

    #pragma unroll
    for (int ks = 0; ks < 3; ++ks) {
        bf16x8 a0 = *(const bf16x8*)(aBase + ks * 32 + lk);
        bf16x8 a1 = *(const bf16x8*)(aBase + 16 * RSTRIDE + ks * 32 + lk);
        #pragma unroll
        for (int ct = 0; ct < 8; ++ct) {
            bf16x8 b = *(const bf16x8*)(bBase + ct * 16 * RSTRIDE + ks * 32 + lk);
            // swapped operands: D fragment lane&15 -> out row, reg -> consecutive out cols
            acc[0][ct] = __builtin_amdgcn_mfma_f32_16x16x32_bf16(b, a0, acc[0][ct], 0, 0, 0);
            acc[1][ct] = __builtin_amdgcn_mfma_f32_16x16x32_bf16(b, a1, acc[1][ct], 0, 0, 0);
        }
    }

    // D layout (swapped): out_row = lane&15 (+rt*16), out_col = (lane>>4)*4 + reg (+ct*16)
    const int cq = (lane >> 4) * 4;
    #pragma unroll
    for (int rt = 0; rt < 2; ++rt) {
        size_t row = (size_t)(bi * BT + w * 32 + rt * 16 + lr);
        float* rowp = out + row * NPTS + (size_t)bj * BT + cq;
        #pragma unroll
        for (int ct = 0; ct < 8; ++ct) {
            __builtin_nontemporal_store(acc[rt][ct], (f32x4*)(rowp + ct * 16));
        }
    }
}

extern "C" void kernel_launch(void* const* d_in, const int* in_sizes, int n_in,
                              void* d_out, int out_size, void* d_ws, size_t ws_size,
                              hipStream_t stream) {
    const float* xs     = (const float*)d_in[0];
    const float* logits = (const float*)d_in[1];
    float* out          = (float*)d_out;
    ushort* psi         = (ushort*)d_ws;   // NPTS * RSTRIDE * 2 = 3.4 MB

    psi_kernel<<<NPTS / 256, 256, 0, stream>>>(xs, logits, psi);

    dim3 grid(NPTS / BT, NPTS / BT);
    gram_kernel<<<grid, 256, 0, stream>>>(psi, out);
}

// Round 3
// 190.713 us; speedup vs baseline: 1.7303x; 1.7303x over previous
//
#include <hip/hip_runtime.h>
#include <hip/hip_bf16.h>
#include <math.h>

#define MAXN    32
#define NPTS    16384
#define NPSI    65              // 2*MAXN+1 feature dim
#define RSTRIDE 104             // ushorts per psi row (208 B, 16B-aligned; K zero-padded to 96)
#define BTA     64              // output tile rows per block
#define BTB     128             // output tile cols per block
#define NROWS   (BTA + BTB)     // 192 staged psi rows
#define NCHUNK  (NROWS * RSTRIDE * 2 / 1024)   // 39 x 1KiB staging chunks

typedef __attribute__((ext_vector_type(8))) short  bf16x8;
typedef __attribute__((ext_vector_type(4))) float  f32x4;

__device__ inline ushort f2bf(float f) {
    union { float f; unsigned u; } v; v.f = f;
    unsigned u = v.u;
    u += 0x7FFFu + ((u >> 16) & 1u);   // round-to-nearest-even
    return (ushort)(u >> 16);
}

// ---------------- kernel 1: psi rows (bf16, padded) into workspace ----------
__global__ __launch_bounds__(256) void psi_kernel(
    const float* __restrict__ xs, const float* __restrict__ logits,
    ushort* __restrict__ psi)
{
    int pt = blockIdx.x * blockDim.x + threadIdx.x;
    if (pt >= NPTS) return;

    float x = xs[pt];
    x = fminf(1.0f, fmaxf(-1.0f, x));
    float s = sqrtf(fmaxf(0.0f, 1.0f - x * x));

    float m = -3.4e38f;
    #pragma unroll
    for (int n = 0; n <= MAXN; ++n) m = fmaxf(m, logits[n]);
    float sum = 0.0f;
    #pragma unroll
    for (int n = 0; n <= MAXN; ++n) sum += __expf(logits[n] - m);
    float inv = 1.0f / sum;

    ushort tmp[RSTRIDE];
    tmp[0] = f2bf(sqrtf(__expf(logits[0] - m) * inv));
    float Tm1 = 1.0f, T = x;        // T_0, T_1
    float Um1 = 1.0f, U = 2.0f * x; // U_0, U_1
    float tx = 2.0f * x;
    #pragma unroll
    for (int n = 1; n <= MAXN; ++n) {
        float swn = sqrtf(__expf(logits[n] - m) * inv);
        tmp[2 * n - 1] = f2bf(swn * T);
        tmp[2 * n]     = f2bf(swn * (s * Um1));
        float Tn = tx * T - Tm1; Tm1 = T; T = Tn;
        float Un = tx * U - Um1; Um1 = U; U = Un;
    }
    #pragma unroll
    for (int k = NPSI; k < RSTRIDE; ++k) tmp[k] = 0;

    unsigned long long* dst = (unsigned long long*)(psi + (size_t)pt * RSTRIDE);
    const unsigned long long* src = (const unsigned long long*)tmp;
    #pragma unroll
    for (int k = 0; k < RSTRIDE / 4; ++k) dst[k] = src[k];
}

// ---------------- kernel 2: gram = psi @ psi^T, 64x128 tile per block -------
__device__ inline void load_lds16(const void* g, void* l) {
    __builtin_amdgcn_global_load_lds(
        (const __attribute__((address_space(1))) unsigned*)g,
        (__attribute__((address_space(3))) unsigned*)l, 16, 0, 0);
}

__global__ __launch_bounds__(256) void gram_kernel(
    const ushort* __restrict__ psi, float* __restrict__ out)
{
    // staging: rows 0..63 = A panel (output rows), rows 64..191 = B panel (output cols)
    // after compute, reused as a 64x128 fp32 tile (32 KB <= 39936 B)
    __shared__ ushort lds[NROWS * RSTRIDE];

    const int tid  = threadIdx.x;
    const int w    = tid >> 6;     // wave 0..3: owns output rows w*16..w*16+15
    const int lane = tid & 63;
    const int bi   = blockIdx.y;   // 0..255 (row tile)
    const int bj   = blockIdx.x;   // 0..127 (col tile)

    // ---- stage 39 x 1KiB chunks (A: 13, B: 26) ----
    {
        const char* gA = (const char*)(psi + (size_t)bi * BTA * RSTRIDE);
        const char* gB = (const char*)(psi + (size_t)bj * BTB * RSTRIDE);
        char* lbase = (char*)lds;
        for (int q = w; q < NCHUNK; q += 4) {
            const char* src = (q < 13) ? (gA + q * 1024) : (gB + (q - 13) * 1024);
            load_lds16(src + lane * 16, lbase + q * 1024);
        }
    }
    __syncthreads();

    const int lr = lane & 15;          // operand row index within 16-tile
    const int lk = (lane >> 4) * 8;    // k offset within 32-k-step
    const int cq = (lane >> 4) * 4;    // output col quad (swapped D layout)

    const ushort* aBase = lds + (w * 16 + lr) * RSTRIDE;
    const ushort* bBase = lds + (BTA + lr) * RSTRIDE;

    f32x4 acc[8];
    #pragma unroll
    for (int ct = 0; ct < 8; ++ct) acc[ct] = (f32x4){0.f, 0.f, 0.f, 0.f};

    #pragma unroll
    for (int ks = 0; ks < 3; ++ks) {
        bf16x8 a = *(const bf16x8*)(aBase + ks * 32 + lk);
        #pragma unroll
        for (int ct = 0; ct < 8; ++ct) {
            bf16x8 b = *(const bf16x8*)(bBase + ct * 16 * RSTRIDE + ks * 32 + lk);
            // swapped operands: D row = lane&15, D col = (lane>>4)*4 + reg
            acc[ct] = __builtin_amdgcn_mfma_f32_16x16x32_bf16(b, a, acc[ct], 0, 0, 0);
        }
    }

    // ---- epilogue: transpose through LDS for 512B-contiguous stores ----
    __syncthreads();   // all waves done reading staged psi
    float* ldsF = (float*)lds;   // [64][128] fp32, XOR-swizzled columns
    {
        const int row = w * 16 + lr;
        const int rx  = (row & 7) << 2;
        #pragma unroll
        for (int ct = 0; ct < 8; ++ct) {
            int col = (cq + ct * 16) ^ rx;
            *(f32x4*)(ldsF + row * BTB + col) = acc[ct];
        }
    }
    __syncthreads();

    // ---- stream out: 8 passes, per-wave-instruction = 2 rows x 512 B ----
    {
        const int rsub = tid >> 5;         // 0..7
        const int col  = (tid & 31) * 4;   // 0..124
        #pragma unroll
        for (int p = 0; p < 8; ++p) {
            int row  = p * 8 + rsub;
            int colr = col ^ ((row & 7) << 2);
            f32x4 v = *(const f32x4*)(ldsF + row * BTB + colr);
            float* dst = out + (size_t)(bi * BTA + row) * NPTS + (size_t)bj * BTB + col;
            *(f32x4*)dst = v;
        }
    }
}

extern "C" void kernel_launch(void* const* d_in, const int* in_sizes, int n_in,
                              void* d_out, int out_size, void* d_ws, size_t ws_size,
                              hipStream_t stream) {
    const float* xs     = (const float*)d_in[0];
    const float* logits = (const float*)d_in[1];
    float* out          = (float*)d_out;
    ushort* psi         = (ushort*)d_ws;   // NPTS * RSTRIDE * 2 = 3.4 MB

    psi_kernel<<<NPTS / 256, 256, 0, stream>>>(xs, logits, psi);

    dim3 grid(NPTS / BTB, NPTS / BTA);
    gram_kernel<<<grid, 256, 0, stream>>>(psi, out);
}